// Round 2
// baseline (1720.830 us; speedup 1.0000x reference)
//
#include <hip/hip_runtime.h>
#include <stdint.h>

// MultiHeadAttention: B=4 S=2048 H=1024 NH=16 HD=64. float32 in/out, int32 mask.
// Outputs concatenated: out (B,S,H) f32 then attn (B,NH,S,S) f32.
// Strategy: split-bf16 (hi+lo, 3-MFMA) for QKV projections and QK^T scores;
// single-bf16 MFMA for PV and output projection.

typedef __attribute__((ext_vector_type(8))) short bf16x8;   // 8 bf16 = 4 VGPRs
typedef __attribute__((ext_vector_type(4))) float f32x4;
typedef unsigned short u16;

#define MFMA16(a,b,c) __builtin_amdgcn_mfma_f32_16x16x32_bf16(a,b,c,0,0,0)

__device__ __forceinline__ float bf2f(u16 u){ union{uint32_t i; float f;} x; x.i=(uint32_t)u<<16; return x.f; }
__device__ __forceinline__ u16 f2bf(float f){ union{float f; uint32_t i;} x; x.f=f; uint32_t r=x.i+0x7fffu+((x.i>>16)&1u); return (u16)(r>>16); }
__device__ __forceinline__ f32x4 zero4(){ f32x4 z = {0.f,0.f,0.f,0.f}; return z; }

// ---------------------------------------------------------------------------
// hsplit: f32 array -> (hi, lo) bf16 arrays. hi = rne(x), lo = rne(x - hi).
// ---------------------------------------------------------------------------
__global__ void hsplit(const float* __restrict__ H, u16* __restrict__ Hi, u16* __restrict__ Lo)
{
    int i = blockIdx.x * 256 + threadIdx.x;          // index in float4 units
    float4 x = ((const float4*)H)[i];
    ushort4 hi, lo;
    u16 h;
    h = f2bf(x.x); hi.x = h; lo.x = f2bf(x.x - bf2f(h));
    h = f2bf(x.y); hi.y = h; lo.y = f2bf(x.y - bf2f(h));
    h = f2bf(x.z); hi.z = h; lo.z = f2bf(x.z - bf2f(h));
    h = f2bf(x.w); hi.w = h; lo.w = f2bf(x.w - bf2f(h));
    ((ushort4*)Hi)[i] = hi;
    ((ushort4*)Lo)[i] = lo;
}

// ---------------------------------------------------------------------------
// wsplit_t: W f32 [1024][1024] -> WT_hi, WT_lo bf16 [1024][1024] (transposed).
// ---------------------------------------------------------------------------
__global__ void wsplit_t(const float* __restrict__ W, u16* __restrict__ Thi, u16* __restrict__ Tlo)
{
    __shared__ float tile[32][33];
    const int c0 = blockIdx.x * 32, r0 = blockIdx.y * 32;
    const int tx = threadIdx.x & 31, ty = threadIdx.x >> 5;   // 32 x 8
    #pragma unroll
    for (int i = 0; i < 32; i += 8)
        tile[ty + i][tx] = W[(size_t)(r0 + ty + i) * 1024 + c0 + tx];
    __syncthreads();
    #pragma unroll
    for (int i = 0; i < 32; i += 8) {
        float x = tile[tx][ty + i];
        u16 h = f2bf(x);
        u16 l = f2bf(x - bf2f(h));
        size_t o = (size_t)(c0 + ty + i) * 1024 + r0 + tx;
        Thi[o] = h; Tlo[o] = l;
    }
}

// ---------------------------------------------------------------------------
// transpose u16: in [batch][R][C] -> out [batch][C][R]  (for V^T)
// ---------------------------------------------------------------------------
__global__ void transpose_k(const u16* __restrict__ in, u16* __restrict__ out, int R, int C)
{
    __shared__ u16 tile[32][33];
    const int batch = blockIdx.z;
    const u16* src = in  + (size_t)batch * R * C;
    u16*       dst = out + (size_t)batch * R * C;
    const int c0 = blockIdx.x * 32, r0 = blockIdx.y * 32;
    const int tx = threadIdx.x & 31, ty = threadIdx.x >> 5;
    #pragma unroll
    for (int i = 0; i < 32; i += 8)
        tile[ty + i][tx] = src[(size_t)(r0 + ty + i) * C + c0 + tx];
    __syncthreads();
    #pragma unroll
    for (int i = 0; i < 32; i += 8)
        dst[(size_t)(c0 + ty + i) * R + r0 + tx] = tile[tx][ty + i];
}

// ---------------------------------------------------------------------------
// gemm3: D = A * Bt^T + bias, split-bf16 (3 MFMAs: hh + hl + lh), M=N=K fixed
// via grid. A as (Ah,Al) [M][1024], Bt as (Bh,Bl) [1024][1024] pre-transposed.
// qkv==1: D written in [B=4][NH=16][S=2048][HD=64] layout as (hi, optional lo).
// qkv==0: unused here (projections only).
// ---------------------------------------------------------------------------
__global__ __launch_bounds__(256, 2)
void gemm3(const u16* __restrict__ Ah, const u16* __restrict__ Al,
           const u16* __restrict__ Bh, const u16* __restrict__ Bl,
           const float* __restrict__ bias,
           u16* __restrict__ Dhi, u16* __restrict__ Dlo)
{
    __shared__ __align__(16) u16 sAh[128 * 32], sAl[128 * 32];
    __shared__ __align__(16) u16 sBh[128 * 32], sBl[128 * 32];
    const int K = 1024;
    const int t = threadIdx.x, lane = t & 63, w = t >> 6;
    const int c = lane & 15, quad = lane >> 4;
    const int m0 = blockIdx.y * 128, n0 = blockIdx.x * 128;
    const int wm = (w & 1) * 64, wn = (w >> 1) * 64;
    const int sw = (c >> 1) & 3;

    f32x4 acc[4][4];
    #pragma unroll
    for (int i = 0; i < 4; i++)
        #pragma unroll
        for (int j = 0; j < 4; j++) acc[i][j] = zero4();

    for (int k0 = 0; k0 < K; k0 += 32) {
        __syncthreads();
        #pragma unroll
        for (int j = 0; j < 2; j++) {
            int ci = j * 256 + t;
            int r = ci >> 2, cc = ci & 3;
            int gc = cc ^ ((r >> 1) & 3);
            size_t ga = (size_t)(m0 + r) * K + k0 + gc * 8;
            size_t gb = (size_t)(n0 + r) * K + k0 + gc * 8;
            *(int4*)(&sAh[ci * 8]) = *(const int4*)(&Ah[ga]);
            *(int4*)(&sAl[ci * 8]) = *(const int4*)(&Al[ga]);
            *(int4*)(&sBh[ci * 8]) = *(const int4*)(&Bh[gb]);
            *(int4*)(&sBl[ci * 8]) = *(const int4*)(&Bl[gb]);
        }
        __syncthreads();

        bf16x8 afh[4], afl[4], bfh[4], bfl[4];
        #pragma unroll
        for (int i = 0; i < 4; i++) {
            int off = (wm + 16 * i + c) * 32 + (quad ^ sw) * 8;
            afh[i] = *(const bf16x8*)(&sAh[off]);
            afl[i] = *(const bf16x8*)(&sAl[off]);
        }
        #pragma unroll
        for (int j = 0; j < 4; j++) {
            int off = (wn + 16 * j + c) * 32 + (quad ^ sw) * 8;
            bfh[j] = *(const bf16x8*)(&sBh[off]);
            bfl[j] = *(const bf16x8*)(&sBl[off]);
        }
        #pragma unroll
        for (int i = 0; i < 4; i++)
            #pragma unroll
            for (int j = 0; j < 4; j++) {
                acc[i][j] = MFMA16(afh[i], bfh[j], acc[i][j]);
                acc[i][j] = MFMA16(afh[i], bfl[j], acc[i][j]);
                acc[i][j] = MFMA16(afl[i], bfh[j], acc[i][j]);
            }
    }

    // epilogue: C/D layout col = lane&15, row = quad*4 + reg; QKV layout out
    #pragma unroll
    for (int j = 0; j < 4; j++) {
        int n = n0 + wn + 16 * j + c;
        float bv = bias[n];
        #pragma unroll
        for (int i = 0; i < 4; i++) {
            #pragma unroll
            for (int r = 0; r < 4; r++) {
                int m = m0 + wm + 16 * i + quad * 4 + r;
                float val = acc[i][j][r] + bv;
                int b = m >> 11, s = m & 2047;
                int nh = n >> 6, d = n & 63;
                size_t o = (((size_t)(b * 16 + nh) * 2048) + s) * 64 + d;
                u16 h = f2bf(val);
                Dhi[o] = h;
                if (Dlo) Dlo[o] = f2bf(val - bf2f(h));
            }
        }
    }
}

// ---------------------------------------------------------------------------
// gemm1: single-bf16 D(f32) = A * Bt^T + bias. For the output projection.
// ---------------------------------------------------------------------------
__global__ __launch_bounds__(256, 2)
void gemm1(const u16* __restrict__ A, const u16* __restrict__ Bt,
           const float* __restrict__ bias, float* __restrict__ D)
{
    __shared__ __align__(16) u16 As[128 * 32];
    __shared__ __align__(16) u16 Bs[128 * 32];
    const int K = 1024, N = 1024;
    const int t = threadIdx.x, lane = t & 63, w = t >> 6;
    const int c = lane & 15, quad = lane >> 4;
    const int m0 = blockIdx.y * 128, n0 = blockIdx.x * 128;
    const int wm = (w & 1) * 64, wn = (w >> 1) * 64;
    const int sw = (c >> 1) & 3;

    f32x4 acc[4][4];
    #pragma unroll
    for (int i = 0; i < 4; i++)
        #pragma unroll
        for (int j = 0; j < 4; j++) acc[i][j] = zero4();

    for (int k0 = 0; k0 < K; k0 += 32) {
        __syncthreads();
        #pragma unroll
        for (int j = 0; j < 2; j++) {
            int ci = j * 256 + t;
            int r = ci >> 2, cc = ci & 3;
            int gc = cc ^ ((r >> 1) & 3);
            *(int4*)(&As[ci * 8]) = *(const int4*)(&A [(size_t)(m0 + r) * K + k0 + gc * 8]);
            *(int4*)(&Bs[ci * 8]) = *(const int4*)(&Bt[(size_t)(n0 + r) * K + k0 + gc * 8]);
        }
        __syncthreads();

        bf16x8 af[4], bfr[4];
        #pragma unroll
        for (int i = 0; i < 4; i++)
            af[i] = *(const bf16x8*)(&As[(wm + 16 * i + c) * 32 + (quad ^ sw) * 8]);
        #pragma unroll
        for (int j = 0; j < 4; j++)
            bfr[j] = *(const bf16x8*)(&Bs[(wn + 16 * j + c) * 32 + (quad ^ sw) * 8]);
        #pragma unroll
        for (int i = 0; i < 4; i++)
            #pragma unroll
            for (int j = 0; j < 4; j++)
                acc[i][j] = MFMA16(af[i], bfr[j], acc[i][j]);
    }

    #pragma unroll
    for (int j = 0; j < 4; j++) {
        int n = n0 + wn + 16 * j + c;
        float bv = bias[n];
        #pragma unroll
        for (int i = 0; i < 4; i++)
            #pragma unroll
            for (int r = 0; r < 4; r++) {
                int m = m0 + wm + 16 * i + quad * 4 + r;
                D[(size_t)m * N + n] = acc[i][j][r] + bv;
            }
    }
}

// ---------------------------------------------------------------------------
// att_fused: per block = 128 q-rows of one (b,h).
// Pass 1: l = sum_k exp(s) with split-bf16 QK^T (6 MFMAs / 16-col tile).
// Pass 2: recompute s, p = exp(s)/l, write attn f32, P->LDS->A-layout, PV MFMA.
// ---------------------------------------------------------------------------
__global__ __launch_bounds__(256, 2)
void att_fused(const u16* __restrict__ Qh, const u16* __restrict__ Ql,
               const u16* __restrict__ Kh, const u16* __restrict__ Kl,
               const u16* __restrict__ Vt, const int* __restrict__ mask,
               float* __restrict__ attn, u16* __restrict__ ctx)
{
    __shared__ __align__(16) u16 KsH[64 * 64], KsL[64 * 64];
    __shared__ __align__(16) u16 Vs[64 * 64];
    __shared__ __align__(16) u16 Ps[128 * 64];
    const int bh = blockIdx.y, b = bh >> 4, h = bh & 15;
    const int q0 = blockIdx.x * 128;
    const int t = threadIdx.x, lane = t & 63, w = t >> 6;
    const int c = lane & 15, quad = lane >> 4;
    const u16* Qhb = Qh + (size_t)bh * 2048 * 64;
    const u16* Qlb = Ql + (size_t)bh * 2048 * 64;
    const u16* Khb = Kh + (size_t)bh * 2048 * 64;
    const u16* Klb = Kl + (size_t)bh * 2048 * 64;
    const u16* Vtb = Vt + (size_t)bh * 64 * 2048;
    const int* mb = mask + b * 2048;

    bf16x8 aqh[2][2], aql[2][2];
    #pragma unroll
    for (int i = 0; i < 2; i++)
        #pragma unroll
        for (int kk = 0; kk < 2; kk++) {
            size_t qoff = (size_t)(q0 + 32 * w + 16 * i + c) * 64 + kk * 32 + quad * 8;
            aqh[i][kk] = *(const bf16x8*)(&Qhb[qoff]);
            aql[i][kk] = *(const bf16x8*)(&Qlb[qoff]);
        }

    // ---- pass 1: row sums ----
    float rs[2][4];
    #pragma unroll
    for (int i = 0; i < 2; i++)
        #pragma unroll
        for (int r = 0; r < 4; r++) rs[i][r] = 0.f;

    for (int k0 = 0; k0 < 2048; k0 += 64) {
        __syncthreads();
        #pragma unroll
        for (int j = 0; j < 2; j++) {
            int ci = j * 256 + t;
            int r = ci >> 3, cc = ci & 7;
            int gc = cc ^ (r & 7);
            size_t g = (size_t)(k0 + r) * 64 + gc * 8;
            *(int4*)(&KsH[ci * 8]) = *(const int4*)(&Khb[g]);
            *(int4*)(&KsL[ci * 8]) = *(const int4*)(&Klb[g]);
        }
        __syncthreads();

        #pragma unroll
        for (int nt = 0; nt < 4; nt++) {
            int kr = 16 * nt + c, swz = kr & 7;
            bf16x8 b0h = *(const bf16x8*)(&KsH[kr * 64 + ((quad    ) ^ swz) * 8]);
            bf16x8 b1h = *(const bf16x8*)(&KsH[kr * 64 + ((quad + 4) ^ swz) * 8]);
            bf16x8 b0l = *(const bf16x8*)(&KsL[kr * 64 + ((quad    ) ^ swz) * 8]);
            bf16x8 b1l = *(const bf16x8*)(&KsL[kr * 64 + ((quad + 4) ^ swz) * 8]);
            int mk = mb[k0 + 16 * nt + c];
            #pragma unroll
            for (int i = 0; i < 2; i++) {
                f32x4 acc = zero4();
                acc = MFMA16(aqh[i][0], b0h, acc);
                acc = MFMA16(aqh[i][0], b0l, acc);
                acc = MFMA16(aql[i][0], b0h, acc);
                acc = MFMA16(aqh[i][1], b1h, acc);
                acc = MFMA16(aqh[i][1], b1l, acc);
                acc = MFMA16(aql[i][1], b1h, acc);
                #pragma unroll
                for (int r = 0; r < 4; r++)
                    rs[i][r] += (mk == 0) ? 0.f : __expf(acc[r] * 0.125f);
            }
        }
    }

    // reduce across the 16 'c' lanes of each quad; all lanes get the sum
    float linv[2][4];
    #pragma unroll
    for (int i = 0; i < 2; i++)
        #pragma unroll
        for (int r = 0; r < 4; r++) {
            float v = rs[i][r];
            #pragma unroll
            for (int off = 1; off < 16; off <<= 1) v += __shfl_xor(v, off, 64);
            linv[i][r] = 1.0f / fmaxf(v, 1e-30f);
        }

    // ---- pass 2: attn + PV ----
    f32x4 cacc[2][4];
    #pragma unroll
    for (int i = 0; i < 2; i++)
        #pragma unroll
        for (int nn = 0; nn < 4; nn++) cacc[i][nn] = zero4();

    for (int k0 = 0; k0 < 2048; k0 += 64) {
        __syncthreads();
        #pragma unroll
        for (int j = 0; j < 2; j++) {
            int ci = j * 256 + t;
            int r = ci >> 3, cc = ci & 7;
            int gc = cc ^ (r & 7);
            size_t g = (size_t)(k0 + r) * 64 + gc * 8;
            *(int4*)(&KsH[ci * 8]) = *(const int4*)(&Khb[g]);
            *(int4*)(&KsL[ci * 8]) = *(const int4*)(&Klb[g]);
            *(int4*)(&Vs [ci * 8]) = *(const int4*)(&Vtb[(size_t)r * 2048 + k0 + gc * 8]);
        }
        __syncthreads();

        #pragma unroll
        for (int nt = 0; nt < 4; nt++) {
            int kr = 16 * nt + c, swz = kr & 7;
            bf16x8 b0h = *(const bf16x8*)(&KsH[kr * 64 + ((quad    ) ^ swz) * 8]);
            bf16x8 b1h = *(const bf16x8*)(&KsH[kr * 64 + ((quad + 4) ^ swz) * 8]);
            bf16x8 b0l = *(const bf16x8*)(&KsL[kr * 64 + ((quad    ) ^ swz) * 8]);
            bf16x8 b1l = *(const bf16x8*)(&KsL[kr * 64 + ((quad + 4) ^ swz) * 8]);
            int mk = mb[k0 + 16 * nt + c];
            #pragma unroll
            for (int i = 0; i < 2; i++) {
                f32x4 acc = zero4();
                acc = MFMA16(aqh[i][0], b0h, acc);
                acc = MFMA16(aqh[i][0], b0l, acc);
                acc = MFMA16(aql[i][0], b0h, acc);
                acc = MFMA16(aqh[i][1], b1h, acc);
                acc = MFMA16(aqh[i][1], b1l, acc);
                acc = MFMA16(aql[i][1], b1h, acc);
                #pragma unroll
                for (int r = 0; r < 4; r++) {
                    float p = (mk == 0) ? 0.f : __expf(acc[r] * 0.125f) * linv[i][r];
                    int qrow = 32 * w + 16 * i + quad * 4 + r;
                    attn[((size_t)bh * 2048 + q0 + qrow) * 2048 + k0 + 16 * nt + c] = p;
                    int kcol = 16 * nt + c;
                    Ps[qrow * 64 + (((kcol >> 3) ^ (qrow & 7)) * 8) + (kcol & 7)] = f2bf(p);
                }
            }
        }

        // PV: ctx += P(128x64) * V(64x64); Ps rows are wave-private
        #pragma unroll
        for (int kk = 0; kk < 2; kk++) {
            bf16x8 ap[2];
            #pragma unroll
            for (int i = 0; i < 2; i++) {
                int row = 32 * w + 16 * i + c;
                ap[i] = *(const bf16x8*)(&Ps[row * 64 + ((kk * 4 + quad) ^ (row & 7)) * 8]);
            }
            #pragma unroll
            for (int nn = 0; nn < 4; nn++) {
                int vr = 16 * nn + c;
                bf16x8 bv = *(const bf16x8*)(&Vs[vr * 64 + ((kk * 4 + quad) ^ (vr & 7)) * 8]);
                #pragma unroll
                for (int i = 0; i < 2; i++)
                    cacc[i][nn] = MFMA16(ap[i], bv, cacc[i][nn]);
            }
        }
    }

    #pragma unroll
    for (int i = 0; i < 2; i++)
        #pragma unroll
        for (int nn = 0; nn < 4; nn++)
            #pragma unroll
            for (int r = 0; r < 4; r++) {
                int qrow = q0 + 32 * w + 16 * i + quad * 4 + r;
                int d = 16 * nn + c;
                ctx[((size_t)b * 2048 + qrow) * 1024 + h * 64 + d] = f2bf(cacc[i][nn][r]);
            }
}

// ---------------------------------------------------------------------------
extern "C" void kernel_launch(void* const* d_in, const int* in_sizes, int n_in,
                              void* d_out, int out_size, void* d_ws, size_t ws_size,
                              hipStream_t stream)
{
    const float* hidden = (const float*)d_in[0];
    const int*   mask   = (const int*)d_in[1];
    const float* Wq = (const float*)d_in[2];
    const float* bq = (const float*)d_in[3];
    const float* Wk = (const float*)d_in[4];
    const float* bk = (const float*)d_in[5];
    const float* Wv = (const float*)d_in[6];
    const float* bv = (const float*)d_in[7];
    const float* Wo = (const float*)d_in[8];
    const float* bo = (const float*)d_in[9];

    u16* ws = (u16*)d_ws;
    u16* WqTh = ws;                   // 8 weight buffers, 1048576 u16 each
    u16* WqTl = WqTh + 1048576;
    u16* WkTh = WqTl + 1048576;
    u16* WkTl = WkTh + 1048576;
    u16* WvTh = WkTl + 1048576;
    u16* WvTl = WvTh + 1048576;
    u16* WoTh = WvTl + 1048576;
    u16* WoTl = WoTh + 1048576;       // written, unused (uniform wsplit_t)
    u16* Hh  = WoTl + 1048576;        // 8388608 u16 each
    u16* Hl  = Hh + 8388608;
    u16* Qhh = Hl + 8388608;
    u16* Qll = Qhh + 8388608;
    u16* Khh = Qll + 8388608;
    u16* Kll = Khh + 8388608;
    u16* Vhh = Kll + 8388608;
    // after the QKV gemms, H is dead: reuse for Vt and ctx
    u16* Vt  = Hh;                    // [bh][64][2048]
    u16* ctx = Hl;                    // [8192][1024] bf16

    float* out  = (float*)d_out;              // 8192*1024
    float* attn = out + 8388608;              // 64*2048*2048

    dim3 tb(256);

    hsplit<<<dim3(8192), tb, 0, stream>>>(hidden, Hh, Hl);
    wsplit_t<<<dim3(32, 32), tb, 0, stream>>>(Wq, WqTh, WqTl);
    wsplit_t<<<dim3(32, 32), tb, 0, stream>>>(Wk, WkTh, WkTl);
    wsplit_t<<<dim3(32, 32), tb, 0, stream>>>(Wv, WvTh, WvTl);
    wsplit_t<<<dim3(32, 32), tb, 0, stream>>>(Wo, WoTh, WoTl);

    gemm3<<<dim3(8, 64), tb, 0, stream>>>(Hh, Hl, WqTh, WqTl, bq, Qhh, Qll);
    gemm3<<<dim3(8, 64), tb, 0, stream>>>(Hh, Hl, WkTh, WkTl, bk, Khh, Kll);
    gemm3<<<dim3(8, 64), tb, 0, stream>>>(Hh, Hl, WvTh, WvTl, bv, Vhh, (u16*)nullptr);

    transpose_k<<<dim3(2, 64, 64), tb, 0, stream>>>(Vhh, Vt, 2048, 64);

    att_fused<<<dim3(16, 64), tb, 0, stream>>>(Qhh, Qll, Khh, Kll, Vt, mask, attn, ctx);

    gemm1<<<dim3(8, 64), tb, 0, stream>>>(ctx, WoTh, bo, out);
}